// Round 7
// baseline (180.114 us; speedup 1.0000x reference)
//
#include <hip/hip_runtime.h>
#include <hip/hip_bf16.h>
#include <math.h>

#define NH 16
#define HS 64
#define DE 1024
#define TT 1024
#define BBATCH 4
#define MTOK 4096   // B*T

typedef __bf16 v8bf __attribute__((ext_vector_type(8)));
typedef __bf16 v4bf __attribute__((ext_vector_type(4)));
typedef float  v4f  __attribute__((ext_vector_type(4)));

__device__ __forceinline__ void gl_lds16(const __bf16* g, __bf16* l) {
    __builtin_amdgcn_global_load_lds(
        (const __attribute__((address_space(1))) unsigned int*)g,
        (__attribute__((address_space(3))) unsigned int*)l, 16, 0, 0);
}

// ---------------- cast fp32 -> bf16, 4 elements/thread ----------------
__global__ __launch_bounds__(256) void cast_bf16_kernel(
    const float* __restrict__ in, __bf16* __restrict__ out, int n4)
{
    int i = blockIdx.x * 256 + threadIdx.x;
    if (i >= n4) return;
    float4 v = ((const float4*)in)[i];
    v4bf o;
    o[0] = (__bf16)v.x; o[1] = (__bf16)v.y; o[2] = (__bf16)v.z; o[3] = (__bf16)v.w;
    *(v4bf*)&out[(size_t)i * 4] = o;
}

// --------- transpose+cast Wq/Wk/Wv [H][C][S] -> Wt[(m*1024+h*64+s)][c] ---------
__global__ __launch_bounds__(256) void prep_w_kernel(
    const float* __restrict__ Wq, const float* __restrict__ Wk,
    const float* __restrict__ Wv, __bf16* __restrict__ Wt)
{
    int m = blockIdx.z, h = blockIdx.y, c0 = blockIdx.x * 64;
    const float* W = (m == 0) ? Wq : (m == 1) ? Wk : Wv;
    __shared__ float tile[64][65];
    int t = threadIdx.x;
    #pragma unroll
    for (int pp = 0; pp < 16; ++pp) {
        int cl = pp * 4 + (t >> 6);
        int s  = t & 63;
        tile[cl][s] = W[((size_t)h * DE + c0 + cl) * HS + s];
    }
    __syncthreads();
    #pragma unroll
    for (int pp = 0; pp < 16; ++pp) {
        int s  = pp * 4 + (t >> 6);
        int cl = t & 63;
        Wt[((size_t)(m * DE + h * HS + s)) * DE + c0 + cl] = (__bf16)tile[cl][s];
    }
}

// ------- 128x128 MFMA GEMM: BK=32 dbuf (32KB LDS -> grid co-resident) + swizzles -------
// LDS: physical 16B chunk p -> row=p>>2, pc=p&3; holds global chunk pc^((row>>1)&3).
// Fragment read of logical chunk lhi hits bank-quad (4*llo + lhi^((llo>>1)&3))%8:
// 8 quads x 2 lanes = 2-way = free. Prefetch of K-tile it+1 issued right after the
// barrier of iter it (drain lands one compute phase later).
__device__ __forceinline__ void gemm_stage(
    const __bf16* __restrict__ Ab, const __bf16* __restrict__ Bb,
    __bf16* As, __bf16* Bs, int K, int k0, int w, int l)
{
    #pragma unroll
    for (int i = 0; i < 2; ++i) {
        int p   = i * 256 + w * 64 + l;        // physical 16B-chunk index, 512 per operand
        int row = p >> 2;
        int lc  = (p & 3) ^ ((row >> 1) & 3);  // logical (global) chunk for this slot
        gl_lds16(Ab + (size_t)row * K + k0 + lc * 8, As + p * 8);
        gl_lds16(Bb + (size_t)row * K + k0 + lc * 8, Bs + p * 8);
    }
}

__global__ __launch_bounds__(256) void gemm_bt_kernel(
    const __bf16* __restrict__ A, const __bf16* __restrict__ Bt,
    int K, int mode,
    __bf16* __restrict__ qk_out, __bf16* __restrict__ vt_out,
    float* __restrict__ f_out, const float* __restrict__ bias)
{
    __shared__ __align__(16) __bf16 As[2][128 * 32];
    __shared__ __align__(16) __bf16 Bs[2][128 * 32];
    const int tid = threadIdx.x;
    const int w = tid >> 6, l = tid & 63;
    const int wm = w >> 1, wn = w & 1;
    const int lhi = l >> 4, llo = l & 15;
    // swizzled element offset within a 32-elem row (logical chunk lhi)
    const int sw = ((lhi ^ ((llo >> 1) & 3)) << 3);

    // XCD-aware swizzle: lin = xcd + 8*(bmi + 4*bn)
    const int lin = blockIdx.x;
    const int xcd = lin & 7, j = lin >> 3;
    const int bm = xcd * 4 + (j & 3);
    const int bn = j >> 2;

    v4f acc[4][4];
    #pragma unroll
    for (int i = 0; i < 4; ++i)
        #pragma unroll
        for (int jj = 0; jj < 4; ++jj)
            #pragma unroll
            for (int r = 0; r < 4; ++r) acc[i][jj][r] = 0.f;

    const __bf16* Ab = A  + (size_t)bm * 128 * K;
    const __bf16* Bb = Bt + (size_t)bn * 128 * K;

    const int niter = K >> 5;
    gemm_stage(Ab, Bb, As[0], Bs[0], K, 0, w, l);

    for (int it = 0; it < niter; ++it) {
        const int buf = it & 1;
        __syncthreads();   // drains this wave's gl_lds for tile `it`; frees buf^1
        if (it + 1 < niter)
            gemm_stage(Ab, Bb, As[buf ^ 1], Bs[buf ^ 1], K, (it + 1) * 32, w, l);
        v8bf a[4], b[4];
        #pragma unroll
        for (int i = 0; i < 4; ++i)
            a[i] = *(const v8bf*)&As[buf][(wm * 64 + i * 16 + llo) * 32 + sw];
        #pragma unroll
        for (int jj = 0; jj < 4; ++jj)
            b[jj] = *(const v8bf*)&Bs[buf][(wn * 64 + jj * 16 + llo) * 32 + sw];
        #pragma unroll
        for (int i = 0; i < 4; ++i)
            #pragma unroll
            for (int jj = 0; jj < 4; ++jj)
                acc[i][jj] = __builtin_amdgcn_mfma_f32_16x16x32_bf16(a[i], b[jj], acc[i][jj], 0, 0, 0);
    }

    const int row0 = bm * 128 + wm * 64;
    const int col0 = bn * 128 + wn * 64;

    if (mode == 0) {
        if (col0 < 2048) {   // Q / K region
            #pragma unroll
            for (int i = 0; i < 4; ++i) {
                int rbase = row0 + i * 16 + lhi * 4;
                #pragma unroll
                for (int jj = 0; jj < 4; ++jj) {
                    int c = col0 + jj * 16 + llo;
                    #pragma unroll
                    for (int r = 0; r < 4; ++r)
                        qk_out[(size_t)(rbase + r) * 2048 + c] = (__bf16)acc[i][jj][r];
                }
            }
        } else {             // V region -> vt[(b*16+h)*64+s][t], packed 4 t's
            #pragma unroll
            for (int i = 0; i < 4; ++i) {
                int rbase = row0 + i * 16 + lhi * 4;
                int bidx = rbase >> 10, t0 = rbase & 1023;
                #pragma unroll
                for (int jj = 0; jj < 4; ++jj) {
                    int c = col0 + jj * 16 + llo - 2048;   // h*64+s
                    v4bf pk;
                    #pragma unroll
                    for (int r = 0; r < 4; ++r) pk[r] = (__bf16)acc[i][jj][r];
                    *(v4bf*)&vt_out[((size_t)(bidx * NH + (c >> 6)) * HS + (c & 63)) * TT + t0] = pk;
                }
            }
        }
    } else {
        #pragma unroll
        for (int jj = 0; jj < 4; ++jj) {
            int c = col0 + jj * 16 + llo;
            float bv = bias[c];
            #pragma unroll
            for (int i = 0; i < 4; ++i) {
                int rbase = row0 + i * 16 + lhi * 4;
                #pragma unroll
                for (int r = 0; r < 4; ++r)
                    f_out[(size_t)(rbase + r) * DE + c] = acc[i][jj][r] + bv;
            }
        }
    }
}

// ---------------- flash attention: dbuf staging + XOR bank swizzle ----------------
__device__ __forceinline__ v4f bf_mfma(v8bf a, v8bf b, v4f c) {
    return __builtin_amdgcn_mfma_f32_16x16x32_bf16(a, b, c, 0, 0, 0);
}

__device__ __forceinline__ void stage_kv(
    const __bf16* __restrict__ kb, const __bf16* __restrict__ vb,
    __bf16* Ksb, __bf16* Vsb, int k0, int tid)
{
    #pragma unroll
    for (int i = 0; i < 2; ++i) {
        int p   = i * 256 + tid;
        int row = p >> 3;
        int lc  = (p & 7) ^ (row & 7);
        gl_lds16(kb + (size_t)(k0 + row) * 2048 + lc * 8, Ksb + p * 8);
        gl_lds16(vb + (size_t)row * TT + k0 + lc * 8,     Vsb + p * 8);
    }
}

template<bool DIAG>
__device__ __forceinline__ void attn_compute(
    const __bf16* __restrict__ Ksb, const __bf16* __restrict__ Vsb,
    __bf16* __restrict__ PsW, int k0, int r0, int lhi, int llo, int sw0, int sw1,
    v8bf aq0, v8bf aq1, v4f (&o)[4], float (&l_part)[4])
{
    v4f sacc[4];
    #pragma unroll
    for (int n = 0; n < 4; ++n)
        #pragma unroll
        for (int r = 0; r < 4; ++r) sacc[n][r] = 0.f;
    #pragma unroll
    for (int n = 0; n < 4; ++n) {
        v8bf bk0 = *(const v8bf*)&Ksb[(n * 16 + llo) * 64 + sw0];
        v8bf bk1 = *(const v8bf*)&Ksb[(n * 16 + llo) * 64 + sw1];
        sacc[n] = bf_mfma(aq0, bk0, sacc[n]);
        sacc[n] = bf_mfma(aq1, bk1, sacc[n]);
    }

    float prob[4][4];
    #pragma unroll
    for (int n = 0; n < 4; ++n) {
        int colg = k0 + n * 16 + llo;
        #pragma unroll
        for (int r = 0; r < 4; ++r) {
            float s2 = sacc[n][r] * 0.18033688f;   // 0.125 * log2(e)
            if (DIAG) { int rowg = r0 + lhi * 4 + r; if (colg > rowg) s2 = -1e30f; }
            float p = exp2f(s2);
            prob[n][r] = p;
            l_part[r] += p;
        }
    }

    #pragma unroll
    for (int r = 0; r < 4; ++r)
        #pragma unroll
        for (int n = 0; n < 4; ++n)
            PsW[(lhi * 4 + r) * 72 + n * 16 + llo] = (__bf16)prob[n][r];

    #pragma unroll
    for (int kk = 0; kk < 64; kk += 32) {
        v8bf ap = *(const v8bf*)&PsW[llo * 72 + kk + lhi * 8];
        const int sw = kk ? sw1 : sw0;
        #pragma unroll
        for (int n = 0; n < 4; ++n) {
            v8bf bv = *(const v8bf*)&Vsb[(n * 16 + llo) * 64 + sw];
            o[n] = bf_mfma(ap, bv, o[n]);
        }
    }
}

__global__ __launch_bounds__(256) void attn_kernel(
    const __bf16* __restrict__ qk, const __bf16* __restrict__ vt,
    __bf16* __restrict__ att)
{
    __shared__ __align__(16) __bf16 Ks[2][64 * 64];
    __shared__ __align__(16) __bf16 Vs[2][64 * 64];
    __shared__ __align__(16) __bf16 Ps[4][16 * 72];

    const int tid = threadIdx.x;
    const int w = tid >> 6, l = tid & 63;
    const int lhi = l >> 4, llo = l & 15;
    const int sw0 = ((lhi ^ (llo & 7)) << 3);
    const int sw1 = sw0 ^ 32;
    const int bh = blockIdx.x & 63;          // same-bh blocks 64 apart -> same XCD
    const int qt = 15 - (blockIdx.x >> 6);   // longest blocks launch first
    const int b = bh >> 4, h = bh & 15;

    const __bf16* qbase = qk + (size_t)b * TT * 2048 + h * HS;
    const __bf16* kbase = qk + (size_t)b * TT * 2048 + 1024 + h * HS;
    const __bf16* vbase = vt + (size_t)bh * HS * TT;
    __bf16* PsW = &Ps[w][0];

    const int r0 = qt * 64 + w * 16;

    stage_kv(kbase, vbase, Ks[0], Vs[0], 0, tid);

    v8bf aq0 = *(const v8bf*)&qbase[(size_t)(r0 + llo) * 2048 + lhi * 8];
    v8bf aq1 = *(const v8bf*)&qbase[(size_t)(r0 + llo) * 2048 + 32 + lhi * 8];

    float l_part[4] = {0.f, 0.f, 0.f, 0.f};
    v4f o[4];
    #pragma unroll
    for (int n = 0; n < 4; ++n)
        #pragma unroll
        for (int r = 0; r < 4; ++r) o[n][r] = 0.f;

    for (int kt = 0; kt < qt; ++kt) {
        const int buf = kt & 1;
        __syncthreads();
        stage_kv(kbase, vbase, Ks[buf ^ 1], Vs[buf ^ 1], (kt + 1) * 64, tid);
        attn_compute<false>(Ks[buf], Vs[buf], PsW, kt * 64, r0, lhi, llo, sw0, sw1, aq0, aq1, o, l_part);
    }
    __syncthreads();
    attn_compute<true>(Ks[qt & 1], Vs[qt & 1], PsW, qt * 64, r0, lhi, llo, sw0, sw1, aq0, aq1, o, l_part);

    #pragma unroll
    for (int r = 0; r < 4; ++r) {
        float s = l_part[r];
        #pragma unroll
        for (int msk = 1; msk < 16; msk <<= 1) s += __shfl_xor(s, msk, 64);
        float inv = 1.f / s;
        int rowg = b * TT + r0 + lhi * 4 + r;
        #pragma unroll
        for (int n = 0; n < 4; ++n)
            att[(size_t)rowg * DE + h * HS + n * 16 + llo] = (__bf16)(o[n][r] * inv);
    }
}

extern "C" void kernel_launch(void* const* d_in, const int* in_sizes, int n_in,
                              void* d_out, int out_size, void* d_ws, size_t ws_size,
                              hipStream_t stream)
{
    const float* x  = (const float*)d_in[0];
    const float* Wq = (const float*)d_in[1];
    const float* Wk = (const float*)d_in[2];
    const float* Wv = (const float*)d_in[3];
    const float* Wo = (const float*)d_in[4];
    const float* bo = (const float*)d_in[5];
    float* out = (float*)d_out;

    char* ws = (char*)d_ws;
    __bf16* xb  = (__bf16*)(ws);                 // 8 MB   [4096][1024]
    __bf16* Wt  = (__bf16*)(ws + 8388608);       // 6 MB   [3072][1024]
    __bf16* Wob = (__bf16*)(ws + 14680064);      // 2 MB   [1024][1024]
    __bf16* qk  = (__bf16*)(ws + 16777216);      // 16 MB  [4096][2048]
    __bf16* vt  = (__bf16*)(ws + 33554432);      // 8 MB   [64][64][1024]
    __bf16* att = (__bf16*)(ws + 41943040);      // 8 MB   [4096][1024]

    cast_bf16_kernel<<<4096, 256, 0, stream>>>(x, xb, 1048576);
    prep_w_kernel<<<dim3(16, 16, 3), 256, 0, stream>>>(Wq, Wk, Wv, Wt);
    cast_bf16_kernel<<<1024, 256, 0, stream>>>(Wo, Wob, 262144);
    // QKV: M=4096, N=3072, K=1024 -> 768 blocks (8 xcd x 4 bm x 24 bn), fully co-resident
    gemm_bt_kernel<<<768, 256, 0, stream>>>(xb, Wt, 1024, 0, qk, vt, nullptr, nullptr);
    // attention: 1024 blocks = 64 bh x 16 q-supertiles, longest first
    attn_kernel<<<1024, 256, 0, stream>>>(qk, vt, att);
    // out proj: M=4096, N=1024, K=1024 -> 256 blocks (8 xcd x 4 bm x 8 bn)
    gemm_bt_kernel<<<256, 256, 0, stream>>>(att, Wob, 1024, 1, nullptr, nullptr, out, bo);
}

// Round 8
// 175.160 us; speedup vs baseline: 1.0283x; 1.0283x over previous
//
#include <hip/hip_runtime.h>
#include <hip/hip_bf16.h>
#include <math.h>

#define NH 16
#define HS 64
#define DE 1024
#define TT 1024
#define BBATCH 4
#define MTOK 4096   // B*T

typedef __bf16 v8bf __attribute__((ext_vector_type(8)));
typedef __bf16 v4bf __attribute__((ext_vector_type(4)));
typedef float  v4f  __attribute__((ext_vector_type(4)));

__device__ __forceinline__ void gl_lds16(const __bf16* g, __bf16* l) {
    __builtin_amdgcn_global_load_lds(
        (const __attribute__((address_space(1))) unsigned int*)g,
        (__attribute__((address_space(3))) unsigned int*)l, 16, 0, 0);
}

// ---------------- cast fp32 -> bf16, 4 elements/thread ----------------
__global__ __launch_bounds__(256) void cast_bf16_kernel(
    const float* __restrict__ in, __bf16* __restrict__ out, int n4)
{
    int i = blockIdx.x * 256 + threadIdx.x;
    if (i >= n4) return;
    float4 v = ((const float4*)in)[i];
    v4bf o;
    o[0] = (__bf16)v.x; o[1] = (__bf16)v.y; o[2] = (__bf16)v.z; o[3] = (__bf16)v.w;
    *(v4bf*)&out[(size_t)i * 4] = o;
}

// --------- transpose+cast Wq/Wk/Wv [H][C][S] -> Wt[(m*1024+h*64+s)][c] ---------
__global__ __launch_bounds__(256) void prep_w_kernel(
    const float* __restrict__ Wq, const float* __restrict__ Wk,
    const float* __restrict__ Wv, __bf16* __restrict__ Wt)
{
    int m = blockIdx.z, h = blockIdx.y, c0 = blockIdx.x * 64;
    const float* W = (m == 0) ? Wq : (m == 1) ? Wk : Wv;
    __shared__ float tile[64][65];
    int t = threadIdx.x;
    #pragma unroll
    for (int pp = 0; pp < 16; ++pp) {
        int cl = pp * 4 + (t >> 6);
        int s  = t & 63;
        tile[cl][s] = W[((size_t)h * DE + c0 + cl) * HS + s];
    }
    __syncthreads();
    #pragma unroll
    for (int pp = 0; pp < 16; ++pp) {
        int s  = pp * 4 + (t >> 6);
        int cl = t & 63;
        Wt[((size_t)(m * DE + h * HS + s)) * DE + c0 + cl] = (__bf16)tile[cl][s];
    }
}

// -------- 128x128 MFMA GEMM: BK=64 dbuf + XCD swizzle + XOR bank swizzle (r6, validated) --------
// BK=64 is the sweet spot: 32 MFMA/wave per barrier. BK=32 regressed (r7): 2x barriers,
// half the work per drain. LDS chunk (row,pc) holds global chunk pc^(row&7).
__device__ __forceinline__ void gemm_stage(
    const __bf16* __restrict__ Ab, const __bf16* __restrict__ Bb,
    __bf16* As, __bf16* Bs, int K, int k0, int w, int l)
{
    #pragma unroll
    for (int i = 0; i < 4; ++i) {
        int p   = i * 256 + w * 64 + l;        // physical 16B-chunk index
        int row = p >> 3;
        int lc  = (p & 7) ^ (row & 7);         // logical (global) chunk for this slot
        gl_lds16(Ab + (size_t)row * K + k0 + lc * 8, As + p * 8);
        gl_lds16(Bb + (size_t)row * K + k0 + lc * 8, Bs + p * 8);
    }
}

__global__ __launch_bounds__(256) void gemm_bt_kernel(
    const __bf16* __restrict__ A, const __bf16* __restrict__ Bt,
    int K, int mode,
    __bf16* __restrict__ qk_out, __bf16* __restrict__ vt_out,
    float* __restrict__ f_out, const float* __restrict__ bias)
{
    __shared__ __align__(16) __bf16 As[2][128 * 64];
    __shared__ __align__(16) __bf16 Bs[2][128 * 64];
    const int tid = threadIdx.x;
    const int w = tid >> 6, l = tid & 63;
    const int wm = w >> 1, wn = w & 1;
    const int lhi = l >> 4, llo = l & 15;
    const int sw0 = ((lhi ^ (llo & 7)) << 3);
    const int sw1 = sw0 ^ 32;

    // XCD-aware swizzle: lin = xcd + 8*(bmi + 4*bn)
    const int lin = blockIdx.x;
    const int xcd = lin & 7, j = lin >> 3;
    const int bm = xcd * 4 + (j & 3);
    const int bn = j >> 2;

    v4f acc[4][4];
    #pragma unroll
    for (int i = 0; i < 4; ++i)
        #pragma unroll
        for (int jj = 0; jj < 4; ++jj)
            #pragma unroll
            for (int r = 0; r < 4; ++r) acc[i][jj][r] = 0.f;

    const __bf16* Ab = A  + (size_t)bm * 128 * K;
    const __bf16* Bb = Bt + (size_t)bn * 128 * K;

    const int niter = K >> 6;
    gemm_stage(Ab, Bb, As[0], Bs[0], K, 0, w, l);

    for (int it = 0; it < niter; ++it) {
        const int buf = it & 1;
        __syncthreads();
        if (it + 1 < niter)
            gemm_stage(Ab, Bb, As[buf ^ 1], Bs[buf ^ 1], K, (it + 1) * 64, w, l);
        #pragma unroll
        for (int kk = 0; kk < 64; kk += 32) {
            const int sw = kk ? sw1 : sw0;
            v8bf a[4], b[4];
            #pragma unroll
            for (int i = 0; i < 4; ++i)
                a[i] = *(const v8bf*)&As[buf][(wm * 64 + i * 16 + llo) * 64 + sw];
            #pragma unroll
            for (int jj = 0; jj < 4; ++jj)
                b[jj] = *(const v8bf*)&Bs[buf][(wn * 64 + jj * 16 + llo) * 64 + sw];
            #pragma unroll
            for (int i = 0; i < 4; ++i)
                #pragma unroll
                for (int jj = 0; jj < 4; ++jj)
                    acc[i][jj] = __builtin_amdgcn_mfma_f32_16x16x32_bf16(a[i], b[jj], acc[i][jj], 0, 0, 0);
        }
    }

    const int row0 = bm * 128 + wm * 64;
    const int col0 = bn * 128 + wn * 64;

    if (mode == 0) {
        if (col0 < 2048) {   // Q / K region
            #pragma unroll
            for (int i = 0; i < 4; ++i) {
                int rbase = row0 + i * 16 + lhi * 4;
                #pragma unroll
                for (int jj = 0; jj < 4; ++jj) {
                    int c = col0 + jj * 16 + llo;
                    #pragma unroll
                    for (int r = 0; r < 4; ++r)
                        qk_out[(size_t)(rbase + r) * 2048 + c] = (__bf16)acc[i][jj][r];
                }
            }
        } else {             // V region -> vt[(b*16+h)*64+s][t], packed 4 t's
            #pragma unroll
            for (int i = 0; i < 4; ++i) {
                int rbase = row0 + i * 16 + lhi * 4;
                int bidx = rbase >> 10, t0 = rbase & 1023;
                #pragma unroll
                for (int jj = 0; jj < 4; ++jj) {
                    int c = col0 + jj * 16 + llo - 2048;   // h*64+s
                    v4bf pk;
                    #pragma unroll
                    for (int r = 0; r < 4; ++r) pk[r] = (__bf16)acc[i][jj][r];
                    *(v4bf*)&vt_out[((size_t)(bidx * NH + (c >> 6)) * HS + (c & 63)) * TT + t0] = pk;
                }
            }
        }
    } else {
        #pragma unroll
        for (int jj = 0; jj < 4; ++jj) {
            int c = col0 + jj * 16 + llo;
            float bv = bias[c];
            #pragma unroll
            for (int i = 0; i < 4; ++i) {
                int rbase = row0 + i * 16 + lhi * 4;
                #pragma unroll
                for (int r = 0; r < 4; ++r)
                    f_out[(size_t)(rbase + r) * DE + c] = acc[i][jj][r] + bv;
            }
        }
    }
}

// -------- flash attention v6: 128-key supertiles, 2 interleaved subtile chains --------
// Per iter: two independent QK->exp->P->PV chains (2x ILP), barrier count halved vs 64-key.
// Last supertile uses DIAG mask; odd halves beyond the diagonal come out fully masked (P=0).
__device__ __forceinline__ v4f bf_mfma(v8bf a, v8bf b, v4f c) {
    return __builtin_amdgcn_mfma_f32_16x16x32_bf16(a, b, c, 0, 0, 0);
}

__device__ __forceinline__ void stage_kv(
    const __bf16* __restrict__ kb, const __bf16* __restrict__ vb,
    __bf16* Ksb, __bf16* Vsb, int k0, int tid)
{
    #pragma unroll
    for (int i = 0; i < 2; ++i) {
        int p   = i * 256 + tid;
        int row = p >> 3;
        int lc  = (p & 7) ^ (row & 7);
        gl_lds16(kb + (size_t)(k0 + row) * 2048 + lc * 8, Ksb + p * 8);
        gl_lds16(vb + (size_t)row * TT + k0 + lc * 8,     Vsb + p * 8);
    }
}

template<bool DIAG>
__device__ __forceinline__ void attn_compute(
    const __bf16* __restrict__ Ksb, const __bf16* __restrict__ Vsb,
    __bf16* __restrict__ PsW, int k0, int r0, int lhi, int llo, int sw0, int sw1,
    v8bf aq0, v8bf aq1, v4f (&o)[4], float (&l_part)[4])
{
    v4f sacc[4];
    #pragma unroll
    for (int n = 0; n < 4; ++n)
        #pragma unroll
        for (int r = 0; r < 4; ++r) sacc[n][r] = 0.f;
    #pragma unroll
    for (int n = 0; n < 4; ++n) {
        v8bf bk0 = *(const v8bf*)&Ksb[(n * 16 + llo) * 64 + sw0];
        v8bf bk1 = *(const v8bf*)&Ksb[(n * 16 + llo) * 64 + sw1];
        sacc[n] = bf_mfma(aq0, bk0, sacc[n]);
        sacc[n] = bf_mfma(aq1, bk1, sacc[n]);
    }

    float prob[4][4];
    #pragma unroll
    for (int n = 0; n < 4; ++n) {
        int colg = k0 + n * 16 + llo;
        #pragma unroll
        for (int r = 0; r < 4; ++r) {
            float s2 = sacc[n][r] * 0.18033688f;   // 0.125 * log2(e)
            if (DIAG) { int rowg = r0 + lhi * 4 + r; if (colg > rowg) s2 = -1e30f; }
            float p = exp2f(s2);
            prob[n][r] = p;
            l_part[r] += p;
        }
    }

    #pragma unroll
    for (int r = 0; r < 4; ++r)
        #pragma unroll
        for (int n = 0; n < 4; ++n)
            PsW[(lhi * 4 + r) * 72 + n * 16 + llo] = (__bf16)prob[n][r];

    #pragma unroll
    for (int kk = 0; kk < 64; kk += 32) {
        v8bf ap = *(const v8bf*)&PsW[llo * 72 + kk + lhi * 8];
        const int sw = kk ? sw1 : sw0;
        #pragma unroll
        for (int n = 0; n < 4; ++n) {
            v8bf bv = *(const v8bf*)&Vsb[(n * 16 + llo) * 64 + sw];
            o[n] = bf_mfma(ap, bv, o[n]);
        }
    }
}

__global__ __launch_bounds__(256) void attn_kernel(
    const __bf16* __restrict__ qk, const __bf16* __restrict__ vt,
    __bf16* __restrict__ att)
{
    __shared__ __align__(16) __bf16 Ks[2][2][64 * 64];  // [buf][sub]
    __shared__ __align__(16) __bf16 Vs[2][2][64 * 64];
    __shared__ __align__(16) __bf16 Ps[4][16 * 72];     // per-wave, reused by both subs

    const int tid = threadIdx.x;
    const int w = tid >> 6, l = tid & 63;
    const int lhi = l >> 4, llo = l & 15;
    const int sw0 = ((lhi ^ (llo & 7)) << 3);
    const int sw1 = sw0 ^ 32;
    const int bh = blockIdx.x & 63;          // same-bh blocks 64 apart -> same XCD
    const int qt = 15 - (blockIdx.x >> 6);   // longest blocks launch first
    const int b = bh >> 4, h = bh & 15;

    const __bf16* qbase = qk + (size_t)b * TT * 2048 + h * HS;
    const __bf16* kbase = qk + (size_t)b * TT * 2048 + 1024 + h * HS;
    const __bf16* vbase = vt + (size_t)bh * HS * TT;
    __bf16* PsW = &Ps[w][0];

    const int r0 = qt * 64 + w * 16;
    const int nkt = (qt + 2) >> 1;           // 128-key supertiles

    // stage supertile 0 (keys 0..127)
    stage_kv(kbase, vbase, Ks[0][0], Vs[0][0], 0,  tid);
    stage_kv(kbase, vbase, Ks[0][1], Vs[0][1], 64, tid);

    v8bf aq0 = *(const v8bf*)&qbase[(size_t)(r0 + llo) * 2048 + lhi * 8];
    v8bf aq1 = *(const v8bf*)&qbase[(size_t)(r0 + llo) * 2048 + 32 + lhi * 8];

    float l_part[4] = {0.f, 0.f, 0.f, 0.f};
    v4f o[4];
    #pragma unroll
    for (int n = 0; n < 4; ++n)
        #pragma unroll
        for (int r = 0; r < 4; ++r) o[n][r] = 0.f;

    for (int st = 0; st < nkt; ++st) {
        const int buf = st & 1;
        const int k0 = st * 128;
        __syncthreads();                     // drains own gl_lds for supertile st
        if (st + 1 < nkt) {
            stage_kv(kbase, vbase, Ks[buf ^ 1][0], Vs[buf ^ 1][0], k0 + 128, tid);
            stage_kv(kbase, vbase, Ks[buf ^ 1][1], Vs[buf ^ 1][1], k0 + 192, tid);
            attn_compute<false>(Ks[buf][0], Vs[buf][0], PsW, k0,      r0, lhi, llo, sw0, sw1, aq0, aq1, o, l_part);
            attn_compute<false>(Ks[buf][1], Vs[buf][1], PsW, k0 + 64, r0, lhi, llo, sw0, sw1, aq0, aq1, o, l_part);
        } else {
            attn_compute<true>(Ks[buf][0], Vs[buf][0], PsW, k0,      r0, lhi, llo, sw0, sw1, aq0, aq1, o, l_part);
            attn_compute<true>(Ks[buf][1], Vs[buf][1], PsW, k0 + 64, r0, lhi, llo, sw0, sw1, aq0, aq1, o, l_part);
        }
    }

    #pragma unroll
    for (int r = 0; r < 4; ++r) {
        float s = l_part[r];
        #pragma unroll
        for (int msk = 1; msk < 16; msk <<= 1) s += __shfl_xor(s, msk, 64);
        float inv = 1.f / s;
        int rowg = b * TT + r0 + lhi * 4 + r;
        #pragma unroll
        for (int n = 0; n < 4; ++n)
            att[(size_t)rowg * DE + h * HS + n * 16 + llo] = (__bf16)(o[n][r] * inv);
    }
}

extern "C" void kernel_launch(void* const* d_in, const int* in_sizes, int n_in,
                              void* d_out, int out_size, void* d_ws, size_t ws_size,
                              hipStream_t stream)
{
    const float* x  = (const float*)d_in[0];
    const float* Wq = (const float*)d_in[1];
    const float* Wk = (const float*)d_in[2];
    const float* Wv = (const float*)d_in[3];
    const float* Wo = (const float*)d_in[4];
    const float* bo = (const float*)d_in[5];
    float* out = (float*)d_out;

    char* ws = (char*)d_ws;
    __bf16* xb  = (__bf16*)(ws);                 // 8 MB   [4096][1024]
    __bf16* Wt  = (__bf16*)(ws + 8388608);       // 6 MB   [3072][1024]
    __bf16* Wob = (__bf16*)(ws + 14680064);      // 2 MB   [1024][1024]
    __bf16* qk  = (__bf16*)(ws + 16777216);      // 16 MB  [4096][2048]
    __bf16* vt  = (__bf16*)(ws + 33554432);      // 8 MB   [64][64][1024]
    __bf16* att = (__bf16*)(ws + 41943040);      // 8 MB   [4096][1024]

    cast_bf16_kernel<<<4096, 256, 0, stream>>>(x, xb, 1048576);
    prep_w_kernel<<<dim3(16, 16, 3), 256, 0, stream>>>(Wq, Wk, Wv, Wt);
    cast_bf16_kernel<<<1024, 256, 0, stream>>>(Wo, Wob, 262144);
    // QKV: M=4096, N=3072, K=1024 -> 768 blocks (8 xcd x 4 bm x 24 bn)
    gemm_bt_kernel<<<768, 256, 0, stream>>>(xb, Wt, 1024, 0, qk, vt, nullptr, nullptr);
    // attention: 1024 blocks = 64 bh x 16 q-supertiles, longest first
    attn_kernel<<<1024, 256, 0, stream>>>(qk, vt, att);
    // out proj: M=4096, N=1024, K=1024 -> 256 blocks (8 xcd x 4 bm x 8 bn)
    gemm_bt_kernel<<<256, 256, 0, stream>>>(att, Wob, 1024, 1, nullptr, nullptr, out, bo);
}

// Round 10
// 167.752 us; speedup vs baseline: 1.0737x; 1.0442x over previous
//
#include <hip/hip_runtime.h>
#include <hip/hip_bf16.h>
#include <math.h>

#define NH 16
#define HS 64
#define DE 1024
#define TT 1024
#define BBATCH 4
#define MTOK 4096   // B*T

typedef __bf16 v8bf __attribute__((ext_vector_type(8)));
typedef __bf16 v4bf __attribute__((ext_vector_type(4)));
typedef float  v4f  __attribute__((ext_vector_type(4)));

__device__ __forceinline__ void gl_lds16(const __bf16* g, __bf16* l) {
    __builtin_amdgcn_global_load_lds(
        (const __attribute__((address_space(1))) unsigned int*)g,
        (__attribute__((address_space(3))) unsigned int*)l, 16, 0, 0);
}

// ---------------- fused prep: cast x (1048576 f4), cast Wo (262144 f4), transpose Wq/Wk/Wv ----
// blocks [0,5120): float4 casts — i<1048576 -> x, else Wo (i-=1048576)
// blocks [5120,5888): W transpose, bid2 = c0i + 16*h + 256*m
__global__ __launch_bounds__(256) void prep_all_kernel(
    const float* __restrict__ x,  __bf16* __restrict__ xb,
    const float* __restrict__ Wo, __bf16* __restrict__ Wob,
    const float* __restrict__ Wq, const float* __restrict__ Wk,
    const float* __restrict__ Wv, __bf16* __restrict__ Wt)
{
    const int bid = blockIdx.x;
    const int t = threadIdx.x;
    if (bid < 5120) {
        int i = bid * 256 + t;
        const float* in; __bf16* out;
        if (i < 1048576) { in = x;  out = xb; }
        else             { in = Wo; out = Wob; i -= 1048576; }
        float4 v = ((const float4*)in)[i];
        v4bf o;
        o[0] = (__bf16)v.x; o[1] = (__bf16)v.y; o[2] = (__bf16)v.z; o[3] = (__bf16)v.w;
        *(v4bf*)&out[(size_t)i * 4] = o;
        return;
    }
    const int bid2 = bid - 5120;
    const int c0 = (bid2 & 15) * 64, h = (bid2 >> 4) & 15, m = bid2 >> 8;
    const float* W = (m == 0) ? Wq : (m == 1) ? Wk : Wv;
    __shared__ float tile[64][65];
    #pragma unroll
    for (int pp = 0; pp < 16; ++pp) {
        int cl = pp * 4 + (t >> 6);
        int s  = t & 63;
        tile[cl][s] = W[((size_t)h * DE + c0 + cl) * HS + s];
    }
    __syncthreads();
    #pragma unroll
    for (int pp = 0; pp < 16; ++pp) {
        int s  = pp * 4 + (t >> 6);
        int cl = t & 63;
        Wt[((size_t)(m * DE + h * HS + s)) * DE + c0 + cl] = (__bf16)tile[cl][s];
    }
}

// -------- 128x128 MFMA GEMM: BK=64 dbuf + XCD swizzle + XOR bank swizzle (r6, validated) --------
// BK=64 sweet spot (r7: BK=32 regressed — barrier amortization beats occupancy here).
// LDS chunk (row,pc) holds global chunk pc^(row&7); conflicts measured ~0.
__device__ __forceinline__ void gemm_stage(
    const __bf16* __restrict__ Ab, const __bf16* __restrict__ Bb,
    __bf16* As, __bf16* Bs, int K, int k0, int w, int l)
{
    #pragma unroll
    for (int i = 0; i < 4; ++i) {
        int p   = i * 256 + w * 64 + l;        // physical 16B-chunk index
        int row = p >> 3;
        int lc  = (p & 7) ^ (row & 7);         // logical (global) chunk for this slot
        gl_lds16(Ab + (size_t)row * K + k0 + lc * 8, As + p * 8);
        gl_lds16(Bb + (size_t)row * K + k0 + lc * 8, Bs + p * 8);
    }
}

__global__ __launch_bounds__(256) void gemm_bt_kernel(
    const __bf16* __restrict__ A, const __bf16* __restrict__ Bt,
    int K, int mode,
    __bf16* __restrict__ qk_out, __bf16* __restrict__ vt_out,
    float* __restrict__ f_out, const float* __restrict__ bias)
{
    __shared__ __align__(16) __bf16 As[2][128 * 64];
    __shared__ __align__(16) __bf16 Bs[2][128 * 64];
    const int tid = threadIdx.x;
    const int w = tid >> 6, l = tid & 63;
    const int wm = w >> 1, wn = w & 1;
    const int lhi = l >> 4, llo = l & 15;
    const int sw0 = ((lhi ^ (llo & 7)) << 3);
    const int sw1 = sw0 ^ 32;

    // XCD-aware swizzle: lin = xcd + 8*(bmi + 4*bn)
    const int lin = blockIdx.x;
    const int xcd = lin & 7, j = lin >> 3;
    const int bm = xcd * 4 + (j & 3);
    const int bn = j >> 2;

    v4f acc[4][4];
    #pragma unroll
    for (int i = 0; i < 4; ++i)
        #pragma unroll
        for (int jj = 0; jj < 4; ++jj)
            #pragma unroll
            for (int r = 0; r < 4; ++r) acc[i][jj][r] = 0.f;

    const __bf16* Ab = A  + (size_t)bm * 128 * K;
    const __bf16* Bb = Bt + (size_t)bn * 128 * K;

    const int niter = K >> 6;
    gemm_stage(Ab, Bb, As[0], Bs[0], K, 0, w, l);

    for (int it = 0; it < niter; ++it) {
        const int buf = it & 1;
        __syncthreads();
        if (it + 1 < niter)
            gemm_stage(Ab, Bb, As[buf ^ 1], Bs[buf ^ 1], K, (it + 1) * 64, w, l);
        #pragma unroll
        for (int kk = 0; kk < 64; kk += 32) {
            const int sw = kk ? sw1 : sw0;
            v8bf a[4], b[4];
            #pragma unroll
            for (int i = 0; i < 4; ++i)
                a[i] = *(const v8bf*)&As[buf][(wm * 64 + i * 16 + llo) * 64 + sw];
            #pragma unroll
            for (int jj = 0; jj < 4; ++jj)
                b[jj] = *(const v8bf*)&Bs[buf][(wn * 64 + jj * 16 + llo) * 64 + sw];
            #pragma unroll
            for (int i = 0; i < 4; ++i)
                #pragma unroll
                for (int jj = 0; jj < 4; ++jj)
                    acc[i][jj] = __builtin_amdgcn_mfma_f32_16x16x32_bf16(a[i], b[jj], acc[i][jj], 0, 0, 0);
        }
    }

    const int row0 = bm * 128 + wm * 64;
    const int col0 = bn * 128 + wn * 64;

    if (mode == 0) {
        if (col0 < 2048) {   // Q / K region
            #pragma unroll
            for (int i = 0; i < 4; ++i) {
                int rbase = row0 + i * 16 + lhi * 4;
                #pragma unroll
                for (int jj = 0; jj < 4; ++jj) {
                    int c = col0 + jj * 16 + llo;
                    #pragma unroll
                    for (int r = 0; r < 4; ++r)
                        qk_out[(size_t)(rbase + r) * 2048 + c] = (__bf16)acc[i][jj][r];
                }
            }
        } else {             // V region -> vt[(b*16+h)*64+s][t], packed 4 t's
            #pragma unroll
            for (int i = 0; i < 4; ++i) {
                int rbase = row0 + i * 16 + lhi * 4;
                int bidx = rbase >> 10, t0 = rbase & 1023;
                #pragma unroll
                for (int jj = 0; jj < 4; ++jj) {
                    int c = col0 + jj * 16 + llo - 2048;   // h*64+s
                    v4bf pk;
                    #pragma unroll
                    for (int r = 0; r < 4; ++r) pk[r] = (__bf16)acc[i][jj][r];
                    *(v4bf*)&vt_out[((size_t)(bidx * NH + (c >> 6)) * HS + (c & 63)) * TT + t0] = pk;
                }
            }
        }
    } else {
        #pragma unroll
        for (int jj = 0; jj < 4; ++jj) {
            int c = col0 + jj * 16 + llo;
            float bv = bias[c];
            #pragma unroll
            for (int i = 0; i < 4; ++i) {
                int rbase = row0 + i * 16 + lhi * 4;
                #pragma unroll
                for (int r = 0; r < 4; ++r)
                    f_out[(size_t)(rbase + r) * DE + c] = acc[i][jj][r] + bv;
            }
        }
    }
}

// ---------------- flash attention v4 (r6-validated best): dbuf staging + XOR swizzle ----------------
__device__ __forceinline__ v4f bf_mfma(v8bf a, v8bf b, v4f c) {
    return __builtin_amdgcn_mfma_f32_16x16x32_bf16(a, b, c, 0, 0, 0);
}

__device__ __forceinline__ void stage_kv(
    const __bf16* __restrict__ kb, const __bf16* __restrict__ vb,
    __bf16* Ksb, __bf16* Vsb, int k0, int tid)
{
    #pragma unroll
    for (int i = 0; i < 2; ++i) {
        int p   = i * 256 + tid;
        int row = p >> 3;
        int lc  = (p & 7) ^ (row & 7);
        gl_lds16(kb + (size_t)(k0 + row) * 2048 + lc * 8, Ksb + p * 8);
        gl_lds16(vb + (size_t)row * TT + k0 + lc * 8,     Vsb + p * 8);
    }
}

template<bool DIAG>
__device__ __forceinline__ void attn_compute(
    const __bf16* __restrict__ Ksb, const __bf16* __restrict__ Vsb,
    __bf16* __restrict__ PsW, int k0, int r0, int lhi, int llo, int sw0, int sw1,
    v8bf aq0, v8bf aq1, v4f (&o)[4], float (&l_part)[4])
{
    v4f sacc[4];
    #pragma unroll
    for (int n = 0; n < 4; ++n)
        #pragma unroll
        for (int r = 0; r < 4; ++r) sacc[n][r] = 0.f;
    #pragma unroll
    for (int n = 0; n < 4; ++n) {
        v8bf bk0 = *(const v8bf*)&Ksb[(n * 16 + llo) * 64 + sw0];
        v8bf bk1 = *(const v8bf*)&Ksb[(n * 16 + llo) * 64 + sw1];
        sacc[n] = bf_mfma(aq0, bk0, sacc[n]);
        sacc[n] = bf_mfma(aq1, bk1, sacc[n]);
    }

    float prob[4][4];
    #pragma unroll
    for (int n = 0; n < 4; ++n) {
        int colg = k0 + n * 16 + llo;
        #pragma unroll
        for (int r = 0; r < 4; ++r) {
            float s2 = sacc[n][r] * 0.18033688f;   // 0.125 * log2(e)
            if (DIAG) { int rowg = r0 + lhi * 4 + r; if (colg > rowg) s2 = -1e30f; }
            float p = exp2f(s2);
            prob[n][r] = p;
            l_part[r] += p;
        }
    }

    #pragma unroll
    for (int r = 0; r < 4; ++r)
        #pragma unroll
        for (int n = 0; n < 4; ++n)
            PsW[(lhi * 4 + r) * 72 + n * 16 + llo] = (__bf16)prob[n][r];

    #pragma unroll
    for (int kk = 0; kk < 64; kk += 32) {
        v8bf ap = *(const v8bf*)&PsW[llo * 72 + kk + lhi * 8];
        const int sw = kk ? sw1 : sw0;
        #pragma unroll
        for (int n = 0; n < 4; ++n) {
            v8bf bv = *(const v8bf*)&Vsb[(n * 16 + llo) * 64 + sw];
            o[n] = bf_mfma(ap, bv, o[n]);
        }
    }
}

__global__ __launch_bounds__(256) void attn_kernel(
    const __bf16* __restrict__ qk, const __bf16* __restrict__ vt,
    __bf16* __restrict__ att)
{
    __shared__ __align__(16) __bf16 Ks[2][64 * 64];
    __shared__ __align__(16) __bf16 Vs[2][64 * 64];
    __shared__ __align__(16) __bf16 Ps[4][16 * 72];

    const int tid = threadIdx.x;
    const int w = tid >> 6, l = tid & 63;
    const int lhi = l >> 4, llo = l & 15;
    const int sw0 = ((lhi ^ (llo & 7)) << 3);
    const int sw1 = sw0 ^ 32;
    const int bh = blockIdx.x & 63;          // same-bh blocks 64 apart -> same XCD
    const int qt = 15 - (blockIdx.x >> 6);   // longest blocks launch first
    const int b = bh >> 4, h = bh & 15;

    const __bf16* qbase = qk + (size_t)b * TT * 2048 + h * HS;
    const __bf16* kbase = qk + (size_t)b * TT * 2048 + 1024 + h * HS;
    const __bf16* vbase = vt + (size_t)bh * HS * TT;
    __bf16* PsW = &Ps[w][0];

    const int r0 = qt * 64 + w * 16;

    stage_kv(kbase, vbase, Ks[0], Vs[0], 0, tid);

    v8bf aq0 = *(const v8bf*)&qbase[(size_t)(r0 + llo) * 2048 + lhi * 8];
    v8bf aq1 = *(const v8bf*)&qbase[(size_t)(r0 + llo) * 2048 + 32 + lhi * 8];

    float l_part[4] = {0.f, 0.f, 0.f, 0.f};
    v4f o[4];
    #pragma unroll
    for (int n = 0; n < 4; ++n)
        #pragma unroll
        for (int r = 0; r < 4; ++r) o[n][r] = 0.f;

    for (int kt = 0; kt < qt; ++kt) {
        const int buf = kt & 1;
        __syncthreads();
        stage_kv(kbase, vbase, Ks[buf ^ 1], Vs[buf ^ 1], (kt + 1) * 64, tid);
        attn_compute<false>(Ks[buf], Vs[buf], PsW, kt * 64, r0, lhi, llo, sw0, sw1, aq0, aq1, o, l_part);
    }
    __syncthreads();
    attn_compute<true>(Ks[qt & 1], Vs[qt & 1], PsW, qt * 64, r0, lhi, llo, sw0, sw1, aq0, aq1, o, l_part);

    #pragma unroll
    for (int r = 0; r < 4; ++r) {
        float s = l_part[r];
        #pragma unroll
        for (int msk = 1; msk < 16; msk <<= 1) s += __shfl_xor(s, msk, 64);
        float inv = 1.f / s;
        int rowg = b * TT + r0 + lhi * 4 + r;
        #pragma unroll
        for (int n = 0; n < 4; ++n)
            att[(size_t)rowg * DE + h * HS + n * 16 + llo] = (__bf16)(o[n][r] * inv);
    }
}

extern "C" void kernel_launch(void* const* d_in, const int* in_sizes, int n_in,
                              void* d_out, int out_size, void* d_ws, size_t ws_size,
                              hipStream_t stream)
{
    const float* x  = (const float*)d_in[0];
    const float* Wq = (const float*)d_in[1];
    const float* Wk = (const float*)d_in[2];
    const float* Wv = (const float*)d_in[3];
    const float* Wo = (const float*)d_in[4];
    const float* bo = (const float*)d_in[5];
    float* out = (float*)d_out;

    char* ws = (char*)d_ws;
    __bf16* xb  = (__bf16*)(ws);                 // 8 MB   [4096][1024]
    __bf16* Wt  = (__bf16*)(ws + 8388608);       // 6 MB   [3072][1024]
    __bf16* Wob = (__bf16*)(ws + 14680064);      // 2 MB   [1024][1024]
    __bf16* qk  = (__bf16*)(ws + 16777216);      // 16 MB  [4096][2048]
    __bf16* vt  = (__bf16*)(ws + 33554432);      // 8 MB   [64][64][1024]
    __bf16* att = (__bf16*)(ws + 41943040);      // 8 MB   [4096][1024]

    // fused prep: casts (5120 blocks) + weight transpose (768 blocks)
    prep_all_kernel<<<5888, 256, 0, stream>>>(x, xb, Wo, Wob, Wq, Wk, Wv, Wt);
    // QKV: M=4096, N=3072, K=1024 -> 768 blocks (8 xcd x 4 bm x 24 bn)
    gemm_bt_kernel<<<768, 256, 0, stream>>>(xb, Wt, 1024, 0, qk, vt, nullptr, nullptr);
    // attention: 1024 blocks = 64 bh x 16 q-supertiles, longest first
    attn_kernel<<<1024, 256, 0, stream>>>(qk, vt, att);
    // out proj: M=4096, N=1024, K=1024 -> 256 blocks (8 xcd x 4 bm x 8 bn)
    gemm_bt_kernel<<<256, 256, 0, stream>>>(att, Wob, 1024, 1, nullptr, nullptr, out, bo);
}